// Round 3
// baseline (503.846 us; speedup 1.0000x reference)
//
#include <hip/hip_runtime.h>
#include <hip/hip_bf16.h>

#define N_NODES 50000
#define E_EDGES 800000
#define S_SAMP 4
#define D_DIM 24
#define NS (N_NODES * S_SAMP)   // 200000

// workspace layout (4-byte units) — total 6,550,512 * 4B = 26.2 MB
#define OFF_AGGX  0                 // N*16 = 800000 floats
#define OFF_AGGC  800000            // N*32 = 1600000 floats
#define OFF_STATS 2400000           // 512 floats
// stats: [0:64) sum_s [64:128) sq_s [128:192) sum_a [192:256) sq_a
//        [256:320) scale_s [320:384) shift_s [384:448) scale_a [448:512) shift_a
#define OFF_DEG   2400512           // 50000 ints (contiguous with stats for one memset)
#define OFF_MA    2450512           // N*64 = 3200000 floats
#define OFF_OFFS  5650512           // 50000 ints
#define OFF_CUR   5700512           // 50000 ints
#define OFF_EIDX  5750512           // 800000 ints

// ---------------------------------------------------------------------------
// CSR build step 1: in-degree histogram
// ---------------------------------------------------------------------------
__global__ __launch_bounds__(256) void hist_kernel(
    const int* __restrict__ ei, int* __restrict__ deg)
{
    int t = blockIdx.x * blockDim.x + threadIdx.x;
    if (t >= E_EDGES) return;
    atomicAdd(&deg[ei[E_EDGES + t]], 1);
}

// ---------------------------------------------------------------------------
// CSR build step 2: exclusive scan of deg (single block, 1024 threads)
// writes offs (row starts) and cur (fill cursors)
// ---------------------------------------------------------------------------
__global__ __launch_bounds__(1024) void scan_kernel(
    const int* __restrict__ deg, int* __restrict__ offs, int* __restrict__ cur)
{
    __shared__ int buf[1024];
    const int t = threadIdx.x;
    const int start = t * 49;                 // 1024*49 = 50176 >= 50000
    const int end = min(start + 49, N_NODES);
    int s = 0;
    for (int i = start; i < end; ++i) s += deg[i];
    buf[t] = s;
    __syncthreads();
    // Hillis-Steele inclusive scan
    for (int off = 1; off < 1024; off <<= 1) {
        int v = (t >= off) ? buf[t - off] : 0;
        __syncthreads();
        buf[t] += v;
        __syncthreads();
    }
    int run = buf[t] - s;                     // exclusive base
    for (int i = start; i < end; ++i) {
        offs[i] = run;
        cur[i] = run;
        run += deg[i];
    }
}

// ---------------------------------------------------------------------------
// CSR build step 3: counting-sort fill of source indices per dst
// ---------------------------------------------------------------------------
__global__ __launch_bounds__(256) void fill_kernel(
    const int* __restrict__ ei, int* __restrict__ cur, int* __restrict__ eidx)
{
    int t = blockIdx.x * blockDim.x + threadIdx.x;
    if (t >= E_EDGES) return;
    int s = ei[t];
    int d = ei[E_EDGES + t];
    int pos = atomicAdd(&cur[d], 1);
    eidx[pos] = s;
}

// ---------------------------------------------------------------------------
// Gather: one wave per node; lanes 0..15 -> x cols, 16..47 -> c cols.
// No atomics; coalesced 64B/128B row reads (L2-resident).
// ---------------------------------------------------------------------------
__global__ __launch_bounds__(256) void gather_kernel(
    const float* __restrict__ x,
    const float* __restrict__ c,
    const int* __restrict__ eidx,
    const int* __restrict__ offs,
    const int* __restrict__ deg,
    float* __restrict__ aggx,
    float* __restrict__ aggc)
{
    const int wave = (blockIdx.x * blockDim.x + threadIdx.x) >> 6;
    const int lane = threadIdx.x & 63;
    if (wave >= N_NODES) return;
    const int n = wave;
    const int start = offs[n];
    const int d = deg[n];

    float acc = 0.f;
    if (lane < 48) {
        const int strd = (lane < 16) ? 16 : 32;
        const float* bp = (lane < 16) ? (x + lane) : (c + lane - 16);
        const int* ep = eidx + start;
#pragma unroll 4
        for (int i = 0; i < d; ++i) {
            int s = ep[i];
            acc += bp[(long long)s * strd];
        }
    }
    if (lane < 16)      aggx[n * 16 + lane] = acc;
    else if (lane < 48) aggc[n * 32 + (lane - 16)] = acc;
}

// ---------------------------------------------------------------------------
// Stats pass (shared/siamese path): rows = N*S -> per-column sum/sumsq
// ---------------------------------------------------------------------------
__global__ __launch_bounds__(256) void stats_shared_kernel(
    const float* __restrict__ x,
    const float* __restrict__ c,
    const float* __restrict__ aggx,
    const float* __restrict__ aggc,
    const float* __restrict__ w1,
    const float* __restrict__ b1,
    const float* __restrict__ epsp,
    float* __restrict__ stats)
{
    __shared__ float sM[256][28];
    __shared__ float sRed[8][64];

    const int tid = threadIdx.x;
    const float eps1 = 1.0f + epsp[0];
    const int r0 = blockIdx.x * 256;
    const int row = r0 + tid;

    if (row < NS) {
        const int n = row >> 2;
        const int s = row & 3;
        const float* xr = x + n * 16;
        const float* ax = aggx + n * 16;
#pragma unroll
        for (int j = 0; j < 16; ++j)
            sM[tid][j] = fmaf(eps1, xr[j], ax[j]);
        const float* cr = c + n * 32 + s * 8;
        const float* ac = aggc + n * 32 + s * 8;
#pragma unroll
        for (int kk = 0; kk < 8; ++kk)
            sM[tid][16 + kk] = fmaf(eps1, cr[kk], ac[kk]);
    }

    const int e = tid & 63;
    const int rg = tid >> 6;
    float wreg[D_DIM];
#pragma unroll
    for (int j = 0; j < D_DIM; ++j)
        wreg[j] = w1[j * 64 + e];
    const float bb = b1[e];

    __syncthreads();

    float lsum = 0.f, lsq = 0.f;
    for (int r = rg; r < 256; r += 4) {
        int rw = r0 + r;
        if (rw >= NS) break;
        float acc = bb;
#pragma unroll
        for (int j = 0; j < D_DIM; ++j)
            acc = fmaf(sM[r][j], wreg[j], acc);
        lsum += acc;
        lsq = fmaf(acc, acc, lsq);
    }
    sRed[rg][e] = lsum;
    sRed[4 + rg][e] = lsq;
    __syncthreads();
    if (rg == 0) {
        float ts = sRed[0][e] + sRed[1][e] + sRed[2][e] + sRed[3][e];
        float tq = sRed[4][e] + sRed[5][e] + sRed[6][e] + sRed[7][e];
        atomicAdd(&stats[e], ts);
        atomicAdd(&stats[64 + e], tq);
    }
}

// ---------------------------------------------------------------------------
// Stats pass (aggregated/mean path): rows = N
// ---------------------------------------------------------------------------
__global__ __launch_bounds__(256) void stats_agg_kernel(
    const float* __restrict__ x,
    const float* __restrict__ c,
    const float* __restrict__ aggx,
    const float* __restrict__ aggc,
    const float* __restrict__ w1,
    const float* __restrict__ b1,
    const float* __restrict__ epsp,
    float* __restrict__ stats)
{
    __shared__ float sM[256][28];
    __shared__ float sRed[8][64];

    const int tid = threadIdx.x;
    const float eps1 = 1.0f + epsp[0];
    const int r0 = blockIdx.x * 256;
    const int row = r0 + tid;

    if (row < N_NODES) {
        const int n = row;
        const float* xr = x + n * 16;
        const float* ax = aggx + n * 16;
#pragma unroll
        for (int j = 0; j < 16; ++j)
            sM[tid][j] = fmaf(eps1, xr[j], ax[j]);
        const float* cr = c + n * 32;
        const float* ac = aggc + n * 32;
#pragma unroll
        for (int kk = 0; kk < 8; ++kk) {
            float sc = 0.f, sa = 0.f;
#pragma unroll
            for (int s = 0; s < 4; ++s) {
                sc += cr[s * 8 + kk];
                sa += ac[s * 8 + kk];
            }
            sM[tid][16 + kk] = 0.25f * fmaf(eps1, sc, sa);
        }
    }

    const int e = tid & 63;
    const int rg = tid >> 6;
    float wreg[D_DIM];
#pragma unroll
    for (int j = 0; j < D_DIM; ++j)
        wreg[j] = w1[j * 64 + e];
    const float bb = b1[e];

    __syncthreads();

    float lsum = 0.f, lsq = 0.f;
    for (int r = rg; r < 256; r += 4) {
        int rw = r0 + r;
        if (rw >= N_NODES) break;
        float acc = bb;
#pragma unroll
        for (int j = 0; j < D_DIM; ++j)
            acc = fmaf(sM[r][j], wreg[j], acc);
        lsum += acc;
        lsq = fmaf(acc, acc, lsq);
    }
    sRed[rg][e] = lsum;
    sRed[4 + rg][e] = lsq;
    __syncthreads();
    if (rg == 0) {
        float ts = sRed[0][e] + sRed[1][e] + sRed[2][e] + sRed[3][e];
        float tq = sRed[4][e] + sRed[5][e] + sRed[6][e] + sRed[7][e];
        atomicAdd(&stats[128 + e], ts);
        atomicAdd(&stats[192 + e], tq);
    }
}

// ---------------------------------------------------------------------------
// Finalize BN statistics -> per-column scale/shift for both paths
// ---------------------------------------------------------------------------
__global__ void bn_finalize_kernel(
    float* __restrict__ stats,
    const float* __restrict__ g1s,
    const float* __restrict__ be1s,
    const float* __restrict__ g1a,
    const float* __restrict__ be1a)
{
    int tid = threadIdx.x;
    if (tid >= 128) return;
    int e = tid & 63;
    int p = tid >> 6;
    float cnt = p ? (float)N_NODES : (float)NS;
    float su = stats[p * 128 + e];
    float sq = stats[p * 128 + 64 + e];
    float mu = su / cnt;
    float var = sq / cnt - mu * mu;
    float rstd = rsqrtf(var + 1e-5f);
    float g = p ? g1a[e] : g1s[e];
    float b = p ? be1a[e] : be1s[e];
    float sc = g * rstd;
    stats[256 + p * 128 + e] = sc;
    stats[256 + p * 128 + 64 + e] = fmaf(-mu, sc, b);
}

// ---------------------------------------------------------------------------
// Pass 2 (agg path): recompute z1a, bn+relu, @W2a + b2a -> ma [N,64] fp32
// ---------------------------------------------------------------------------
__global__ __launch_bounds__(256) void mlp2_agg_kernel(
    const float* __restrict__ x,
    const float* __restrict__ c,
    const float* __restrict__ aggx,
    const float* __restrict__ aggc,
    const float* __restrict__ w1,
    const float* __restrict__ b1,
    const float* __restrict__ epsp,
    const float* __restrict__ stats,
    const float* __restrict__ w2,
    const float* __restrict__ b2,
    float* __restrict__ ma)
{
    __shared__ float sM[64][28];
    __shared__ float sH[64 * 64];

    const int tid = threadIdx.x;
    const float eps1 = 1.0f + epsp[0];
    const int r0 = blockIdx.x * 64;
    const float* scale = stats + 384;
    const float* shift = stats + 448;

    for (int i = tid; i < 64 * 24; i += 256) {
        int r = i / 24, j = i % 24;
        int n = r0 + r;
        float v = 0.f;
        if (n < N_NODES) {
            if (j < 16) {
                v = fmaf(eps1, x[n * 16 + j], aggx[n * 16 + j]);
            } else {
                int kk = j - 16;
                float sc = 0.f, sa = 0.f;
#pragma unroll
                for (int s = 0; s < 4; ++s) {
                    sc += c[n * 32 + s * 8 + kk];
                    sa += aggc[n * 32 + s * 8 + kk];
                }
                v = 0.25f * fmaf(eps1, sc, sa);
            }
        }
        sM[r][j] = v;
    }

    const int e = tid & 63;
    const int rg = tid >> 6;

    __syncthreads();

    {
        float w1reg[D_DIM];
#pragma unroll
        for (int j = 0; j < D_DIM; ++j)
            w1reg[j] = w1[j * 64 + e];
        const float b1e = b1[e];
        const float sce = scale[e], she = shift[e];
        for (int r = rg; r < 64; r += 4) {
            float acc = b1e;
#pragma unroll
            for (int j = 0; j < D_DIM; ++j)
                acc = fmaf(sM[r][j], w1reg[j], acc);
            sH[r * 64 + e] = fmaxf(fmaf(acc, sce, she), 0.f);
        }
    }
    __syncthreads();

    {
        float w2reg[64];
#pragma unroll
        for (int k = 0; k < 64; ++k)
            w2reg[k] = w2[k * 64 + e];
        const float b2e = b2[e];
        for (int r = rg; r < 64; r += 4) {
            int rw = r0 + r;
            if (rw >= N_NODES) break;
            float acc = b2e;
#pragma unroll
            for (int k = 0; k < 64; ++k)
                acc = fmaf(sH[r * 64 + k], w2reg[k], acc);
            ma[rw * 64 + e] = acc;
        }
    }
}

// ---------------------------------------------------------------------------
// Pass 2 (shared path) + DSS combine -> out [NS,64] fp32
// ---------------------------------------------------------------------------
__global__ __launch_bounds__(256) void mlp2_shared_kernel(
    const float* __restrict__ x,
    const float* __restrict__ c,
    const float* __restrict__ aggx,
    const float* __restrict__ aggc,
    const float* __restrict__ w1,
    const float* __restrict__ b1,
    const float* __restrict__ epsp,
    const float* __restrict__ stats,
    const float* __restrict__ w2,
    const float* __restrict__ b2,
    const float* __restrict__ ma,
    float* __restrict__ out)
{
    __shared__ float sM[64][28];
    __shared__ float sH[64 * 64];

    const int tid = threadIdx.x;
    const float eps1 = 1.0f + epsp[0];
    const int r0 = blockIdx.x * 64;
    const float* scale = stats + 256;
    const float* shift = stats + 320;

    for (int i = tid; i < 64 * 24; i += 256) {
        int r = i / 24, j = i % 24;
        int rw = r0 + r;
        float v = 0.f;
        if (rw < NS) {
            int n = rw >> 2;
            int s = rw & 3;
            if (j < 16) {
                v = fmaf(eps1, x[n * 16 + j], aggx[n * 16 + j]);
            } else {
                int kk = j - 16;
                v = fmaf(eps1, c[n * 32 + s * 8 + kk], aggc[n * 32 + s * 8 + kk]);
            }
        }
        sM[r][j] = v;
    }

    const int e = tid & 63;
    const int rg = tid >> 6;

    __syncthreads();

    {
        float w1reg[D_DIM];
#pragma unroll
        for (int j = 0; j < D_DIM; ++j)
            w1reg[j] = w1[j * 64 + e];
        const float b1e = b1[e];
        const float sce = scale[e], she = shift[e];
        for (int r = rg; r < 64; r += 4) {
            float acc = b1e;
#pragma unroll
            for (int j = 0; j < D_DIM; ++j)
                acc = fmaf(sM[r][j], w1reg[j], acc);
            sH[r * 64 + e] = fmaxf(fmaf(acc, sce, she), 0.f);
        }
    }
    __syncthreads();

    {
        float w2reg[64];
#pragma unroll
        for (int k = 0; k < 64; ++k)
            w2reg[k] = w2[k * 64 + e];
        const float b2e = b2[e];
        for (int r = rg; r < 64; r += 4) {
            int rw = r0 + r;
            if (rw >= NS) break;
            float acc = b2e + ma[(rw >> 2) * 64 + e];
#pragma unroll
            for (int k = 0; k < 64; ++k)
                acc = fmaf(sH[r * 64 + k], w2reg[k], acc);
            out[rw * 64 + e] = acc;
        }
    }
}

// ---------------------------------------------------------------------------
extern "C" void kernel_launch(void* const* d_in, const int* in_sizes, int n_in,
                              void* d_out, int out_size, void* d_ws, size_t ws_size,
                              hipStream_t stream)
{
    const float* x    = (const float*)d_in[0];
    const float* c    = (const float*)d_in[1];
    const int*   ei   = (const int*)d_in[2];
    const float* epsS = (const float*)d_in[3];
    const float* W1s  = (const float*)d_in[4];
    const float* b1s  = (const float*)d_in[5];
    const float* g1s  = (const float*)d_in[6];
    const float* be1s = (const float*)d_in[7];
    const float* W2s  = (const float*)d_in[8];
    const float* b2s  = (const float*)d_in[9];
    const float* epsA = (const float*)d_in[10];
    const float* W1a  = (const float*)d_in[11];
    const float* b1a  = (const float*)d_in[12];
    const float* g1a  = (const float*)d_in[13];
    const float* be1a = (const float*)d_in[14];
    const float* W2a  = (const float*)d_in[15];
    const float* b2a  = (const float*)d_in[16];

    float* ws    = (float*)d_ws;
    float* aggx  = ws + OFF_AGGX;
    float* aggc  = ws + OFF_AGGC;
    float* stats = ws + OFF_STATS;
    float* ma    = ws + OFF_MA;
    int*   deg   = (int*)ws + OFF_DEG;
    int*   offs  = (int*)ws + OFF_OFFS;
    int*   cur   = (int*)ws + OFF_CUR;
    int*   eidx  = (int*)ws + OFF_EIDX;

    // zero stats + deg (contiguous, 202 KB); agg buffers are overwritten by gather
    hipMemsetAsync(stats, 0, (size_t)(512 + N_NODES) * sizeof(float), stream);

    // CSR build + gather (replaces fp32 atomic scatter)
    hist_kernel<<<(E_EDGES + 255) / 256, 256, 0, stream>>>(ei, deg);
    scan_kernel<<<1, 1024, 0, stream>>>(deg, offs, cur);
    fill_kernel<<<(E_EDGES + 255) / 256, 256, 0, stream>>>(ei, cur, eidx);
    gather_kernel<<<(N_NODES * 64 + 255) / 256, 256, 0, stream>>>(
        x, c, eidx, offs, deg, aggx, aggc);

    // BN stats passes
    stats_shared_kernel<<<(NS + 255) / 256, 256, 0, stream>>>(
        x, c, aggx, aggc, W1s, b1s, epsS, stats);
    stats_agg_kernel<<<(N_NODES + 255) / 256, 256, 0, stream>>>(
        x, c, aggx, aggc, W1a, b1a, epsA, stats);

    bn_finalize_kernel<<<1, 128, 0, stream>>>(stats, g1s, be1s, g1a, be1a);

    // Pass 2
    mlp2_agg_kernel<<<(N_NODES + 63) / 64, 256, 0, stream>>>(
        x, c, aggx, aggc, W1a, b1a, epsA, stats, W2a, b2a, ma);

    mlp2_shared_kernel<<<(NS + 63) / 64, 256, 0, stream>>>(
        x, c, aggx, aggc, W1s, b1s, epsS, stats, W2s, b2s, ma, (float*)d_out);
}

// Round 4
// 380.163 us; speedup vs baseline: 1.3253x; 1.3253x over previous
//
#include <hip/hip_runtime.h>
#include <hip/hip_bf16.h>

#define N_NODES 50000
#define E_EDGES 800000
#define S_SAMP 4
#define D_DIM 24
#define NS (N_NODES * S_SAMP)   // 200000

// workspace layout (4-byte units) — total ~16.6 MB
#define OFF_AGGX  0                 // N*16 = 800000 floats
#define OFF_AGGC  800000            // N*32 = 1600000 floats
#define OFF_STATS 2400000           // 512 floats
// stats: [0:64) sum_s [64:128) sq_s [128:192) sum_a [192:256) sq_a
//        [256:320) scale_s [320:384) shift_s [384:448) scale_a [448:512) shift_a
#define OFF_DEG   2400512           // 50000 ints
#define OFF_CNT   2450512           // 16 ints (counter; memset covers stats..cnt)
#define OFF_OFFS  2450528           // 50000 ints
#define OFF_CUR   2500528           // 50000 ints
#define OFF_EIDX  2550528           // 800000 ints

// ---------------------------------------------------------------------------
// CSR build step 1: in-degree histogram
// ---------------------------------------------------------------------------
__global__ __launch_bounds__(256) void hist_kernel(
    const int* __restrict__ ei, int* __restrict__ deg)
{
    int t = blockIdx.x * blockDim.x + threadIdx.x;
    if (t >= E_EDGES) return;
    atomicAdd(&deg[ei[E_EDGES + t]], 1);
}

// ---------------------------------------------------------------------------
// CSR build step 2: region allocation. Order does NOT matter — each node just
// needs a disjoint contiguous slice of eidx. Block-local scan + one global
// atomic per block (196 blocks, full occupancy; replaces 111us serial scan).
// ---------------------------------------------------------------------------
__global__ __launch_bounds__(256) void alloc_kernel(
    const int* __restrict__ deg, int* __restrict__ offs,
    int* __restrict__ cur, int* __restrict__ counter)
{
    __shared__ int buf[256];
    __shared__ int base;
    const int t = threadIdx.x;
    const int n = blockIdx.x * 256 + t;
    const int d = (n < N_NODES) ? deg[n] : 0;
    buf[t] = d;
    __syncthreads();
    for (int off = 1; off < 256; off <<= 1) {
        int v = (t >= off) ? buf[t - off] : 0;
        __syncthreads();
        buf[t] += v;
        __syncthreads();
    }
    if (t == 255) base = atomicAdd(counter, buf[255]);
    __syncthreads();
    if (n < N_NODES) {
        int pos = base + buf[t] - d;   // exclusive within block + block base
        offs[n] = pos;
        cur[n] = pos;
    }
}

// ---------------------------------------------------------------------------
// CSR build step 3: counting-sort fill of source indices per dst
// ---------------------------------------------------------------------------
__global__ __launch_bounds__(256) void fill_kernel(
    const int* __restrict__ ei, int* __restrict__ cur, int* __restrict__ eidx)
{
    int t = blockIdx.x * blockDim.x + threadIdx.x;
    if (t >= E_EDGES) return;
    int s = ei[t];
    int d = ei[E_EDGES + t];
    int pos = atomicAdd(&cur[d], 1);
    eidx[pos] = s;
}

// ---------------------------------------------------------------------------
// Gather: one wave per node; lanes 0..15 -> x cols, 16..47 -> c cols.
// ---------------------------------------------------------------------------
__global__ __launch_bounds__(256) void gather_kernel(
    const float* __restrict__ x,
    const float* __restrict__ c,
    const int* __restrict__ eidx,
    const int* __restrict__ offs,
    const int* __restrict__ deg,
    float* __restrict__ aggx,
    float* __restrict__ aggc)
{
    const int wave = (blockIdx.x * blockDim.x + threadIdx.x) >> 6;
    const int lane = threadIdx.x & 63;
    if (wave >= N_NODES) return;
    const int n = wave;
    const int start = offs[n];
    const int d = deg[n];

    float acc = 0.f;
    if (lane < 48) {
        const int strd = (lane < 16) ? 16 : 32;
        const float* bp = (lane < 16) ? (x + lane) : (c + lane - 16);
        const int* ep = eidx + start;
#pragma unroll 4
        for (int i = 0; i < d; ++i) {
            int s = ep[i];
            acc += bp[(long long)s * strd];
        }
    }
    if (lane < 16)      aggx[n * 16 + lane] = acc;
    else if (lane < 48) aggc[n * 32 + (lane - 16)] = acc;
}

// ---------------------------------------------------------------------------
// Stats pass (shared/siamese path): rows = N*S -> per-column sum/sumsq
// ---------------------------------------------------------------------------
__global__ __launch_bounds__(256) void stats_shared_kernel(
    const float* __restrict__ x,
    const float* __restrict__ c,
    const float* __restrict__ aggx,
    const float* __restrict__ aggc,
    const float* __restrict__ w1,
    const float* __restrict__ b1,
    const float* __restrict__ epsp,
    float* __restrict__ stats)
{
    __shared__ float sM[256][28];
    __shared__ float sRed[8][64];

    const int tid = threadIdx.x;
    const float eps1 = 1.0f + epsp[0];
    const int r0 = blockIdx.x * 256;
    const int row = r0 + tid;

    if (row < NS) {
        const int n = row >> 2;
        const int s = row & 3;
        const float* xr = x + n * 16;
        const float* ax = aggx + n * 16;
#pragma unroll
        for (int j = 0; j < 16; ++j)
            sM[tid][j] = fmaf(eps1, xr[j], ax[j]);
        const float* cr = c + n * 32 + s * 8;
        const float* ac = aggc + n * 32 + s * 8;
#pragma unroll
        for (int kk = 0; kk < 8; ++kk)
            sM[tid][16 + kk] = fmaf(eps1, cr[kk], ac[kk]);
    }

    const int e = tid & 63;
    const int rg = tid >> 6;
    float wreg[D_DIM];
#pragma unroll
    for (int j = 0; j < D_DIM; ++j)
        wreg[j] = w1[j * 64 + e];
    const float bb = b1[e];

    __syncthreads();

    float lsum = 0.f, lsq = 0.f;
    for (int r = rg; r < 256; r += 4) {
        int rw = r0 + r;
        if (rw >= NS) break;
        float acc = bb;
#pragma unroll
        for (int j = 0; j < D_DIM; ++j)
            acc = fmaf(sM[r][j], wreg[j], acc);
        lsum += acc;
        lsq = fmaf(acc, acc, lsq);
    }
    sRed[rg][e] = lsum;
    sRed[4 + rg][e] = lsq;
    __syncthreads();
    if (rg == 0) {
        float ts = sRed[0][e] + sRed[1][e] + sRed[2][e] + sRed[3][e];
        float tq = sRed[4][e] + sRed[5][e] + sRed[6][e] + sRed[7][e];
        atomicAdd(&stats[e], ts);
        atomicAdd(&stats[64 + e], tq);
    }
}

// ---------------------------------------------------------------------------
// Stats pass (aggregated/mean path): rows = N
// ---------------------------------------------------------------------------
__global__ __launch_bounds__(256) void stats_agg_kernel(
    const float* __restrict__ x,
    const float* __restrict__ c,
    const float* __restrict__ aggx,
    const float* __restrict__ aggc,
    const float* __restrict__ w1,
    const float* __restrict__ b1,
    const float* __restrict__ epsp,
    float* __restrict__ stats)
{
    __shared__ float sM[256][28];
    __shared__ float sRed[8][64];

    const int tid = threadIdx.x;
    const float eps1 = 1.0f + epsp[0];
    const int r0 = blockIdx.x * 256;
    const int row = r0 + tid;

    if (row < N_NODES) {
        const int n = row;
        const float* xr = x + n * 16;
        const float* ax = aggx + n * 16;
#pragma unroll
        for (int j = 0; j < 16; ++j)
            sM[tid][j] = fmaf(eps1, xr[j], ax[j]);
        const float* cr = c + n * 32;
        const float* ac = aggc + n * 32;
#pragma unroll
        for (int kk = 0; kk < 8; ++kk) {
            float sc = 0.f, sa = 0.f;
#pragma unroll
            for (int s = 0; s < 4; ++s) {
                sc += cr[s * 8 + kk];
                sa += ac[s * 8 + kk];
            }
            sM[tid][16 + kk] = 0.25f * fmaf(eps1, sc, sa);
        }
    }

    const int e = tid & 63;
    const int rg = tid >> 6;
    float wreg[D_DIM];
#pragma unroll
    for (int j = 0; j < D_DIM; ++j)
        wreg[j] = w1[j * 64 + e];
    const float bb = b1[e];

    __syncthreads();

    float lsum = 0.f, lsq = 0.f;
    for (int r = rg; r < 256; r += 4) {
        int rw = r0 + r;
        if (rw >= N_NODES) break;
        float acc = bb;
#pragma unroll
        for (int j = 0; j < D_DIM; ++j)
            acc = fmaf(sM[r][j], wreg[j], acc);
        lsum += acc;
        lsq = fmaf(acc, acc, lsq);
    }
    sRed[rg][e] = lsum;
    sRed[4 + rg][e] = lsq;
    __syncthreads();
    if (rg == 0) {
        float ts = sRed[0][e] + sRed[1][e] + sRed[2][e] + sRed[3][e];
        float tq = sRed[4][e] + sRed[5][e] + sRed[6][e] + sRed[7][e];
        atomicAdd(&stats[128 + e], ts);
        atomicAdd(&stats[192 + e], tq);
    }
}

// ---------------------------------------------------------------------------
// Finalize BN statistics -> per-column scale/shift for both paths
// ---------------------------------------------------------------------------
__global__ void bn_finalize_kernel(
    float* __restrict__ stats,
    const float* __restrict__ g1s,
    const float* __restrict__ be1s,
    const float* __restrict__ g1a,
    const float* __restrict__ be1a)
{
    int tid = threadIdx.x;
    if (tid >= 128) return;
    int e = tid & 63;
    int p = tid >> 6;
    float cnt = p ? (float)N_NODES : (float)NS;
    float su = stats[p * 128 + e];
    float sq = stats[p * 128 + 64 + e];
    float mu = su / cnt;
    float var = sq / cnt - mu * mu;
    float rstd = rsqrtf(var + 1e-5f);
    float g = p ? g1a[e] : g1s[e];
    float b = p ? be1a[e] : be1s[e];
    float sc = g * rstd;
    stats[256 + p * 128 + e] = sc;
    stats[256 + p * 128 + 64 + e] = fmaf(-mu, sc, b);
}

// ---------------------------------------------------------------------------
// Fused pass 2: block = 64 shared rows = exactly 16 nodes (50000 = 3125*16).
// Agg-path inputs derived in-LDS from shared-path rows (x part = row 4n,
// c part = mean over the 4 sample rows). Computes ma in-block, then the
// shared path + DSS combine -> out. No ma buffer, no bounds checks (exact).
// ---------------------------------------------------------------------------
__global__ __launch_bounds__(256) void mlp2_fused_kernel(
    const float* __restrict__ x,
    const float* __restrict__ c,
    const float* __restrict__ aggx,
    const float* __restrict__ aggc,
    const float* __restrict__ w1s,
    const float* __restrict__ b1s,
    const float* __restrict__ epsS,
    const float* __restrict__ w1a,
    const float* __restrict__ b1a,
    const float* __restrict__ epsA,
    const float* __restrict__ stats,
    const float* __restrict__ w2s,
    const float* __restrict__ b2s,
    const float* __restrict__ w2a,
    const float* __restrict__ b2a,
    float* __restrict__ out)
{
    __shared__ float sM[64][28];     // shared-path inputs (64 rows x 24)
    __shared__ float sMa[16][28];    // agg-path inputs (16 nodes x 24)
    __shared__ float sHa[16 * 64];   // agg hidden
    __shared__ float sMA[16 * 64];   // ma result
    __shared__ float sH[64 * 64];    // shared hidden

    const int tid = threadIdx.x;
    const float e1s = 1.0f + epsS[0];
    const float e1a = 1.0f + epsA[0];
    const int r0 = blockIdx.x * 64;          // global shared-row base
    const int e = tid & 63;
    const int rg = tid >> 6;

    // build shared-path input rows (agg uses eps_agg on the same feat/agg mix,
    // so store feat and agg contributions... note eps differs between paths ->
    // sM uses e1s; sMa recomputed from raw x/c/agg below with e1a)
    for (int i = tid; i < 64 * 24; i += 256) {
        int r = i / 24, j = i % 24;
        int rw = r0 + r;
        int n = rw >> 2;
        int s = rw & 3;
        float v;
        if (j < 16) v = fmaf(e1s, x[n * 16 + j], aggx[n * 16 + j]);
        else {
            int kk = j - 16;
            v = fmaf(e1s, c[n * 32 + s * 8 + kk], aggc[n * 32 + s * 8 + kk]);
        }
        sM[r][j] = v;
    }
    // agg-path input rows (16 nodes), direct from global (eps_agg)
    for (int i = tid; i < 16 * 24; i += 256) {
        int r = i / 24, j = i % 24;
        int n = (r0 >> 2) + r;
        float v;
        if (j < 16) v = fmaf(e1a, x[n * 16 + j], aggx[n * 16 + j]);
        else {
            int kk = j - 16;
            float sc = 0.f, sa = 0.f;
#pragma unroll
            for (int s = 0; s < 4; ++s) {
                sc += c[n * 32 + s * 8 + kk];
                sa += aggc[n * 32 + s * 8 + kk];
            }
            v = 0.25f * fmaf(e1a, sc, sa);
        }
        sMa[r][j] = v;
    }
    __syncthreads();

    // --- agg path: matmul1 + bn + relu -> sHa ---
    {
        float wr[D_DIM];
#pragma unroll
        for (int j = 0; j < D_DIM; ++j) wr[j] = w1a[j * 64 + e];
        const float bb = b1a[e];
        const float sce = stats[384 + e], she = stats[448 + e];
#pragma unroll
        for (int r = rg; r < 16; r += 4) {
            float acc = bb;
#pragma unroll
            for (int j = 0; j < D_DIM; ++j)
                acc = fmaf(sMa[r][j], wr[j], acc);
            sHa[r * 64 + e] = fmaxf(fmaf(acc, sce, she), 0.f);
        }
    }
    __syncthreads();

    // --- agg path: matmul2 -> sMA (= ma + b2a) ---
    {
        float wr[64];
#pragma unroll
        for (int k = 0; k < 64; ++k) wr[k] = w2a[k * 64 + e];
        const float bb = b2a[e];
#pragma unroll
        for (int r = rg; r < 16; r += 4) {
            float acc = bb;
#pragma unroll
            for (int k = 0; k < 64; ++k)
                acc = fmaf(sHa[r * 64 + k], wr[k], acc);
            sMA[r * 64 + e] = acc;
        }
    }

    // --- shared path: matmul1 + bn + relu -> sH (no sync needed vs sMA:
    // sMA written/read by same (e,rg) partition? combine reads all nodes ->
    // sync required before combine; matmul1 touches only sM/sH) ---
    {
        float wr[D_DIM];
#pragma unroll
        for (int j = 0; j < D_DIM; ++j) wr[j] = w1s[j * 64 + e];
        const float bb = b1s[e];
        const float sce = stats[256 + e], she = stats[320 + e];
#pragma unroll
        for (int r = rg; r < 64; r += 4) {
            float acc = bb;
#pragma unroll
            for (int j = 0; j < D_DIM; ++j)
                acc = fmaf(sM[r][j], wr[j], acc);
            sH[r * 64 + e] = fmaxf(fmaf(acc, sce, she), 0.f);
        }
    }
    __syncthreads();

    // --- shared path: matmul2 + DSS combine -> out ---
    {
        float wr[64];
#pragma unroll
        for (int k = 0; k < 64; ++k) wr[k] = w2s[k * 64 + e];
        const float bb = b2s[e];
#pragma unroll
        for (int r = rg; r < 64; r += 4) {
            float acc = bb + sMA[(r >> 2) * 64 + e];
#pragma unroll
            for (int k = 0; k < 64; ++k)
                acc = fmaf(sH[r * 64 + k], wr[k], acc);
            out[(r0 + r) * 64 + e] = acc;
        }
    }
}

// ---------------------------------------------------------------------------
extern "C" void kernel_launch(void* const* d_in, const int* in_sizes, int n_in,
                              void* d_out, int out_size, void* d_ws, size_t ws_size,
                              hipStream_t stream)
{
    const float* x    = (const float*)d_in[0];
    const float* c    = (const float*)d_in[1];
    const int*   ei   = (const int*)d_in[2];
    const float* epsS = (const float*)d_in[3];
    const float* W1s  = (const float*)d_in[4];
    const float* b1s  = (const float*)d_in[5];
    const float* g1s  = (const float*)d_in[6];
    const float* be1s = (const float*)d_in[7];
    const float* W2s  = (const float*)d_in[8];
    const float* b2s  = (const float*)d_in[9];
    const float* epsA = (const float*)d_in[10];
    const float* W1a  = (const float*)d_in[11];
    const float* b1a  = (const float*)d_in[12];
    const float* g1a  = (const float*)d_in[13];
    const float* be1a = (const float*)d_in[14];
    const float* W2a  = (const float*)d_in[15];
    const float* b2a  = (const float*)d_in[16];

    float* ws    = (float*)d_ws;
    float* aggx  = ws + OFF_AGGX;
    float* aggc  = ws + OFF_AGGC;
    float* stats = ws + OFF_STATS;
    int*   deg   = (int*)ws + OFF_DEG;
    int*   cnt   = (int*)ws + OFF_CNT;
    int*   offs  = (int*)ws + OFF_OFFS;
    int*   cur   = (int*)ws + OFF_CUR;
    int*   eidx  = (int*)ws + OFF_EIDX;

    // zero stats + deg + counter (contiguous)
    hipMemsetAsync(stats, 0, (size_t)(512 + N_NODES + 16) * sizeof(float), stream);

    // CSR build + gather
    hist_kernel<<<(E_EDGES + 255) / 256, 256, 0, stream>>>(ei, deg);
    alloc_kernel<<<(N_NODES + 255) / 256, 256, 0, stream>>>(deg, offs, cur, cnt);
    fill_kernel<<<(E_EDGES + 255) / 256, 256, 0, stream>>>(ei, cur, eidx);
    gather_kernel<<<(N_NODES * 64 + 255) / 256, 256, 0, stream>>>(
        x, c, eidx, offs, deg, aggx, aggc);

    // BN stats passes
    stats_shared_kernel<<<(NS + 255) / 256, 256, 0, stream>>>(
        x, c, aggx, aggc, W1s, b1s, epsS, stats);
    stats_agg_kernel<<<(N_NODES + 255) / 256, 256, 0, stream>>>(
        x, c, aggx, aggc, W1a, b1a, epsA, stats);

    bn_finalize_kernel<<<1, 128, 0, stream>>>(stats, g1s, be1s, g1a, be1a);

    // Fused pass 2 -> out
    mlp2_fused_kernel<<<N_NODES / 16, 256, 0, stream>>>(
        x, c, aggx, aggc, W1s, b1s, epsS, W1a, b1a, epsA, stats,
        W2s, b2s, W2a, b2a, (float*)d_out);
}

// Round 5
// 368.836 us; speedup vs baseline: 1.3660x; 1.0307x over previous
//
#include <hip/hip_runtime.h>
#include <hip/hip_bf16.h>

#define N_NODES 50000
#define E_EDGES 800000
#define S_SAMP 4
#define D_DIM 24
#define NS (N_NODES * S_SAMP)   // 200000

// workspace layout (4-byte units)
#define OFF_AGGX  0                 // N*16 = 800000 floats
#define OFF_AGGC  800000            // N*32 = 1600000 floats
#define OFF_STATS 2400000           // 512 floats
// stats: [0:64) sum_s [64:128) sq_s [128:192) sum_a [192:256) sq_a
//        [256:320) scale_s [320:384) shift_s [384:448) scale_a [448:512) shift_a
#define OFF_DEG   2400512           // 50000 ints
#define OFF_CNT   2450512           // 16 ints (memset covers stats..cnt)
#define OFF_OFFS  2450528           // 50000 ints
#define OFF_CUR   2500528           // 50000 ints
#define OFF_EIDX  2550528           // 800000 ints

// ---------------------------------------------------------------------------
// CSR build step 1: in-degree histogram
// ---------------------------------------------------------------------------
__global__ __launch_bounds__(256) void hist_kernel(
    const int* __restrict__ ei, int* __restrict__ deg)
{
    int t = blockIdx.x * blockDim.x + threadIdx.x;
    if (t >= E_EDGES) return;
    atomicAdd(&deg[ei[E_EDGES + t]], 1);
}

// ---------------------------------------------------------------------------
// CSR build step 2: disjoint region allocation (order irrelevant for gather):
// block-local scan + one global atomic per block.
// ---------------------------------------------------------------------------
__global__ __launch_bounds__(256) void alloc_kernel(
    const int* __restrict__ deg, int* __restrict__ offs,
    int* __restrict__ cur, int* __restrict__ counter)
{
    __shared__ int buf[256];
    __shared__ int base;
    const int t = threadIdx.x;
    const int n = blockIdx.x * 256 + t;
    const int d = (n < N_NODES) ? deg[n] : 0;
    buf[t] = d;
    __syncthreads();
    for (int off = 1; off < 256; off <<= 1) {
        int v = (t >= off) ? buf[t - off] : 0;
        __syncthreads();
        buf[t] += v;
        __syncthreads();
    }
    if (t == 255) base = atomicAdd(counter, buf[255]);
    __syncthreads();
    if (n < N_NODES) {
        int pos = base + buf[t] - d;
        offs[n] = pos;
        cur[n] = pos;
    }
}

// ---------------------------------------------------------------------------
// CSR build step 3: counting-sort fill of source indices per dst
// ---------------------------------------------------------------------------
__global__ __launch_bounds__(256) void fill_kernel(
    const int* __restrict__ ei, int* __restrict__ cur, int* __restrict__ eidx)
{
    int t = blockIdx.x * blockDim.x + threadIdx.x;
    if (t >= E_EDGES) return;
    int s = ei[t];
    int d = ei[E_EDGES + t];
    int pos = atomicAdd(&cur[d], 1);
    eidx[pos] = s;
}

// ---------------------------------------------------------------------------
// Gather: one wave per node; lanes 0..15 -> x cols, 16..47 -> c cols.
// ---------------------------------------------------------------------------
__global__ __launch_bounds__(256) void gather_kernel(
    const float* __restrict__ x,
    const float* __restrict__ c,
    const int* __restrict__ eidx,
    const int* __restrict__ offs,
    const int* __restrict__ deg,
    float* __restrict__ aggx,
    float* __restrict__ aggc)
{
    const int wave = (blockIdx.x * blockDim.x + threadIdx.x) >> 6;
    const int lane = threadIdx.x & 63;
    if (wave >= N_NODES) return;
    const int n = wave;
    const int start = offs[n];
    const int d = deg[n];

    float acc = 0.f;
    if (lane < 48) {
        const int strd = (lane < 16) ? 16 : 32;
        const float* bp = (lane < 16) ? (x + lane) : (c + lane - 16);
        const int* ep = eidx + start;
#pragma unroll 4
        for (int i = 0; i < d; ++i) {
            int s = ep[i];
            acc += bp[(long long)s * strd];
        }
    }
    if (lane < 16)      aggx[n * 16 + lane] = acc;
    else if (lane < 48) aggc[n * 32 + (lane - 16)] = acc;
}

// ---------------------------------------------------------------------------
// Fused BN-stats pass: one block = 256 shared rows = 64 nodes.
// Computes per-column sum/sumsq of z1 for BOTH paths (shared + agg).
// 4-way split accumulators break the 24-long FMA dependency chains.
// ---------------------------------------------------------------------------
__global__ __launch_bounds__(256) void stats_fused_kernel(
    const float* __restrict__ x,
    const float* __restrict__ c,
    const float* __restrict__ aggx,
    const float* __restrict__ aggc,
    const float* __restrict__ w1s,
    const float* __restrict__ b1s,
    const float* __restrict__ epsS,
    const float* __restrict__ w1a,
    const float* __restrict__ b1a,
    const float* __restrict__ epsA,
    float* __restrict__ stats)
{
    __shared__ float sM[256][28];    // shared-path rows
    __shared__ float sMa[64][28];    // agg-path rows
    __shared__ float sRed[16][64];

    const int tid = threadIdx.x;
    const float e1s = 1.0f + epsS[0];
    const float e1a = 1.0f + epsA[0];
    const int r0 = blockIdx.x * 256;   // shared-row base
    const int n0 = r0 >> 2;            // node base (64 nodes)
    const int row = r0 + tid;

    // phase A1: shared-path row for this thread
    if (row < NS) {
        const int n = row >> 2;
        const int s = row & 3;
        const float* xr = x + n * 16;
        const float* ax = aggx + n * 16;
#pragma unroll
        for (int j = 0; j < 16; ++j)
            sM[tid][j] = fmaf(e1s, xr[j], ax[j]);
        const float* cr = c + n * 32 + s * 8;
        const float* ac = aggc + n * 32 + s * 8;
#pragma unroll
        for (int kk = 0; kk < 8; ++kk)
            sM[tid][16 + kk] = fmaf(e1s, cr[kk], ac[kk]);
    }
    // phase A2: agg-path rows (64 nodes x 24 = 1536 items)
    for (int i = tid; i < 64 * 24; i += 256) {
        int r = i / 24, j = i % 24;
        int n = n0 + r;
        float v = 0.f;
        if (n < N_NODES) {
            if (j < 16) {
                v = fmaf(e1a, x[n * 16 + j], aggx[n * 16 + j]);
            } else {
                int kk = j - 16;
                float sc = 0.f, sa = 0.f;
#pragma unroll
                for (int s = 0; s < 4; ++s) {
                    sc += c[n * 32 + s * 8 + kk];
                    sa += aggc[n * 32 + s * 8 + kk];
                }
                v = 0.25f * fmaf(e1a, sc, sa);
            }
        }
        sMa[r][j] = v;
    }

    const int e = tid & 63;
    const int rg = tid >> 6;
    __syncthreads();

    // phase B1: shared-path partials (64 rows per thread)
    {
        float wr[D_DIM];
#pragma unroll
        for (int j = 0; j < D_DIM; ++j) wr[j] = w1s[j * 64 + e];
        const float bb = b1s[e];
        float lsum = 0.f, lsq = 0.f;
        for (int r = rg; r < 256; r += 4) {
            if (r0 + r >= NS) break;
            float a0 = 0.f, a1 = 0.f, a2 = 0.f, a3 = 0.f;
#pragma unroll
            for (int j = 0; j < 6; ++j) {
                a0 = fmaf(sM[r][j],      wr[j],      a0);
                a1 = fmaf(sM[r][j + 6],  wr[j + 6],  a1);
                a2 = fmaf(sM[r][j + 12], wr[j + 12], a2);
                a3 = fmaf(sM[r][j + 18], wr[j + 18], a3);
            }
            float acc = bb + ((a0 + a1) + (a2 + a3));
            lsum += acc;
            lsq = fmaf(acc, acc, lsq);
        }
        sRed[rg][e] = lsum;
        sRed[4 + rg][e] = lsq;
    }
    // phase B2: agg-path partials (16 rows per thread)
    {
        float wr[D_DIM];
#pragma unroll
        for (int j = 0; j < D_DIM; ++j) wr[j] = w1a[j * 64 + e];
        const float bb = b1a[e];
        float lsum = 0.f, lsq = 0.f;
        for (int r = rg; r < 64; r += 4) {
            if (n0 + r >= N_NODES) break;
            float a0 = 0.f, a1 = 0.f, a2 = 0.f, a3 = 0.f;
#pragma unroll
            for (int j = 0; j < 6; ++j) {
                a0 = fmaf(sMa[r][j],      wr[j],      a0);
                a1 = fmaf(sMa[r][j + 6],  wr[j + 6],  a1);
                a2 = fmaf(sMa[r][j + 12], wr[j + 12], a2);
                a3 = fmaf(sMa[r][j + 18], wr[j + 18], a3);
            }
            float acc = bb + ((a0 + a1) + (a2 + a3));
            lsum += acc;
            lsq = fmaf(acc, acc, lsq);
        }
        sRed[8 + rg][e] = lsum;
        sRed[12 + rg][e] = lsq;
    }
    __syncthreads();
    if (rg == 0) {
        float t0 = (sRed[0][e] + sRed[1][e]) + (sRed[2][e] + sRed[3][e]);
        float t1 = (sRed[4][e] + sRed[5][e]) + (sRed[6][e] + sRed[7][e]);
        float t2 = (sRed[8][e] + sRed[9][e]) + (sRed[10][e] + sRed[11][e]);
        float t3 = (sRed[12][e] + sRed[13][e]) + (sRed[14][e] + sRed[15][e]);
        atomicAdd(&stats[e], t0);
        atomicAdd(&stats[64 + e], t1);
        atomicAdd(&stats[128 + e], t2);
        atomicAdd(&stats[192 + e], t3);
    }
}

// ---------------------------------------------------------------------------
// Finalize BN statistics -> per-column scale/shift for both paths
// ---------------------------------------------------------------------------
__global__ void bn_finalize_kernel(
    float* __restrict__ stats,
    const float* __restrict__ g1s,
    const float* __restrict__ be1s,
    const float* __restrict__ g1a,
    const float* __restrict__ be1a)
{
    int tid = threadIdx.x;
    if (tid >= 128) return;
    int e = tid & 63;
    int p = tid >> 6;
    float cnt = p ? (float)N_NODES : (float)NS;
    float su = stats[p * 128 + e];
    float sq = stats[p * 128 + 64 + e];
    float mu = su / cnt;
    float var = sq / cnt - mu * mu;
    float rstd = rsqrtf(var + 1e-5f);
    float g = p ? g1a[e] : g1s[e];
    float b = p ? be1a[e] : be1s[e];
    float sc = g * rstd;
    stats[256 + p * 128 + e] = sc;
    stats[256 + p * 128 + 64 + e] = fmaf(-mu, sc, b);
}

// ---------------------------------------------------------------------------
// Fused pass 2: block = 64 shared rows = 16 nodes (50000 = 3125*16 exact).
// Computes agg path (ma) in-block, then shared path + DSS combine -> out.
// All matmul loops use 4 split accumulators (chains 64->16, 24->6).
// ---------------------------------------------------------------------------
__global__ __launch_bounds__(256) void mlp2_fused_kernel(
    const float* __restrict__ x,
    const float* __restrict__ c,
    const float* __restrict__ aggx,
    const float* __restrict__ aggc,
    const float* __restrict__ w1s,
    const float* __restrict__ b1s,
    const float* __restrict__ epsS,
    const float* __restrict__ w1a,
    const float* __restrict__ b1a,
    const float* __restrict__ epsA,
    const float* __restrict__ stats,
    const float* __restrict__ w2s,
    const float* __restrict__ b2s,
    const float* __restrict__ w2a,
    const float* __restrict__ b2a,
    float* __restrict__ out)
{
    __shared__ float sM[64][28];     // shared-path inputs
    __shared__ float sMa[16][28];    // agg-path inputs
    __shared__ float sHa[16 * 64];   // agg hidden
    __shared__ float sMA[16 * 64];   // ma result
    __shared__ float sH[64 * 64];    // shared hidden

    const int tid = threadIdx.x;
    const float e1s = 1.0f + epsS[0];
    const float e1a = 1.0f + epsA[0];
    const int r0 = blockIdx.x * 64;
    const int e = tid & 63;
    const int rg = tid >> 6;

    for (int i = tid; i < 64 * 24; i += 256) {
        int r = i / 24, j = i % 24;
        int rw = r0 + r;
        int n = rw >> 2;
        int s = rw & 3;
        float v;
        if (j < 16) v = fmaf(e1s, x[n * 16 + j], aggx[n * 16 + j]);
        else {
            int kk = j - 16;
            v = fmaf(e1s, c[n * 32 + s * 8 + kk], aggc[n * 32 + s * 8 + kk]);
        }
        sM[r][j] = v;
    }
    for (int i = tid; i < 16 * 24; i += 256) {
        int r = i / 24, j = i % 24;
        int n = (r0 >> 2) + r;
        float v;
        if (j < 16) v = fmaf(e1a, x[n * 16 + j], aggx[n * 16 + j]);
        else {
            int kk = j - 16;
            float sc = 0.f, sa = 0.f;
#pragma unroll
            for (int s = 0; s < 4; ++s) {
                sc += c[n * 32 + s * 8 + kk];
                sa += aggc[n * 32 + s * 8 + kk];
            }
            v = 0.25f * fmaf(e1a, sc, sa);
        }
        sMa[r][j] = v;
    }
    __syncthreads();

    // --- agg path: matmul1 + bn + relu -> sHa ---
    {
        float wr[D_DIM];
#pragma unroll
        for (int j = 0; j < D_DIM; ++j) wr[j] = w1a[j * 64 + e];
        const float bb = b1a[e];
        const float sce = stats[384 + e], she = stats[448 + e];
#pragma unroll
        for (int r = rg; r < 16; r += 4) {
            float a0 = 0.f, a1 = 0.f, a2 = 0.f, a3 = 0.f;
#pragma unroll
            for (int j = 0; j < 6; ++j) {
                a0 = fmaf(sMa[r][j],      wr[j],      a0);
                a1 = fmaf(sMa[r][j + 6],  wr[j + 6],  a1);
                a2 = fmaf(sMa[r][j + 12], wr[j + 12], a2);
                a3 = fmaf(sMa[r][j + 18], wr[j + 18], a3);
            }
            float acc = bb + ((a0 + a1) + (a2 + a3));
            sHa[r * 64 + e] = fmaxf(fmaf(acc, sce, she), 0.f);
        }
    }
    __syncthreads();

    // --- agg path: matmul2 -> sMA ---
    {
        float wr[64];
#pragma unroll
        for (int k = 0; k < 64; ++k) wr[k] = w2a[k * 64 + e];
        const float bb = b2a[e];
#pragma unroll
        for (int r = rg; r < 16; r += 4) {
            float a0 = 0.f, a1 = 0.f, a2 = 0.f, a3 = 0.f;
#pragma unroll
            for (int k = 0; k < 16; ++k) {
                a0 = fmaf(sHa[r * 64 + k],      wr[k],      a0);
                a1 = fmaf(sHa[r * 64 + k + 16], wr[k + 16], a1);
                a2 = fmaf(sHa[r * 64 + k + 32], wr[k + 32], a2);
                a3 = fmaf(sHa[r * 64 + k + 48], wr[k + 48], a3);
            }
            sMA[r * 64 + e] = bb + ((a0 + a1) + (a2 + a3));
        }
    }

    // --- shared path: matmul1 + bn + relu -> sH ---
    {
        float wr[D_DIM];
#pragma unroll
        for (int j = 0; j < D_DIM; ++j) wr[j] = w1s[j * 64 + e];
        const float bb = b1s[e];
        const float sce = stats[256 + e], she = stats[320 + e];
#pragma unroll
        for (int r = rg; r < 64; r += 4) {
            float a0 = 0.f, a1 = 0.f, a2 = 0.f, a3 = 0.f;
#pragma unroll
            for (int j = 0; j < 6; ++j) {
                a0 = fmaf(sM[r][j],      wr[j],      a0);
                a1 = fmaf(sM[r][j + 6],  wr[j + 6],  a1);
                a2 = fmaf(sM[r][j + 12], wr[j + 12], a2);
                a3 = fmaf(sM[r][j + 18], wr[j + 18], a3);
            }
            float acc = bb + ((a0 + a1) + (a2 + a3));
            sH[r * 64 + e] = fmaxf(fmaf(acc, sce, she), 0.f);
        }
    }
    __syncthreads();

    // --- shared path: matmul2 + DSS combine -> out ---
    {
        float wr[64];
#pragma unroll
        for (int k = 0; k < 64; ++k) wr[k] = w2s[k * 64 + e];
        const float bb = b2s[e];
#pragma unroll
        for (int r = rg; r < 64; r += 4) {
            float a0 = 0.f, a1 = 0.f, a2 = 0.f, a3 = 0.f;
#pragma unroll
            for (int k = 0; k < 16; ++k) {
                a0 = fmaf(sH[r * 64 + k],      wr[k],      a0);
                a1 = fmaf(sH[r * 64 + k + 16], wr[k + 16], a1);
                a2 = fmaf(sH[r * 64 + k + 32], wr[k + 32], a2);
                a3 = fmaf(sH[r * 64 + k + 48], wr[k + 48], a3);
            }
            float acc = bb + sMA[(r >> 2) * 64 + e] + ((a0 + a1) + (a2 + a3));
            out[(r0 + r) * 64 + e] = acc;
        }
    }
}

// ---------------------------------------------------------------------------
extern "C" void kernel_launch(void* const* d_in, const int* in_sizes, int n_in,
                              void* d_out, int out_size, void* d_ws, size_t ws_size,
                              hipStream_t stream)
{
    const float* x    = (const float*)d_in[0];
    const float* c    = (const float*)d_in[1];
    const int*   ei   = (const int*)d_in[2];
    const float* epsS = (const float*)d_in[3];
    const float* W1s  = (const float*)d_in[4];
    const float* b1s  = (const float*)d_in[5];
    const float* g1s  = (const float*)d_in[6];
    const float* be1s = (const float*)d_in[7];
    const float* W2s  = (const float*)d_in[8];
    const float* b2s  = (const float*)d_in[9];
    const float* epsA = (const float*)d_in[10];
    const float* W1a  = (const float*)d_in[11];
    const float* b1a  = (const float*)d_in[12];
    const float* g1a  = (const float*)d_in[13];
    const float* be1a = (const float*)d_in[14];
    const float* W2a  = (const float*)d_in[15];
    const float* b2a  = (const float*)d_in[16];

    float* ws    = (float*)d_ws;
    float* aggx  = ws + OFF_AGGX;
    float* aggc  = ws + OFF_AGGC;
    float* stats = ws + OFF_STATS;
    int*   deg   = (int*)ws + OFF_DEG;
    int*   cnt   = (int*)ws + OFF_CNT;
    int*   offs  = (int*)ws + OFF_OFFS;
    int*   cur   = (int*)ws + OFF_CUR;
    int*   eidx  = (int*)ws + OFF_EIDX;

    // zero stats + deg + counter (contiguous)
    hipMemsetAsync(stats, 0, (size_t)(512 + N_NODES + 16) * sizeof(float), stream);

    // CSR build + gather
    hist_kernel<<<(E_EDGES + 255) / 256, 256, 0, stream>>>(ei, deg);
    alloc_kernel<<<(N_NODES + 255) / 256, 256, 0, stream>>>(deg, offs, cur, cnt);
    fill_kernel<<<(E_EDGES + 255) / 256, 256, 0, stream>>>(ei, cur, eidx);
    gather_kernel<<<(N_NODES * 64 + 255) / 256, 256, 0, stream>>>(
        x, c, eidx, offs, deg, aggx, aggc);

    // fused BN stats (both paths)
    stats_fused_kernel<<<(NS + 255) / 256, 256, 0, stream>>>(
        x, c, aggx, aggc, W1s, b1s, epsS, W1a, b1a, epsA, stats);

    bn_finalize_kernel<<<1, 128, 0, stream>>>(stats, g1s, be1s, g1a, be1a);

    // fused pass 2 -> out
    mlp2_fused_kernel<<<N_NODES / 16, 256, 0, stream>>>(
        x, c, aggx, aggc, W1s, b1s, epsS, W1a, b1a, epsA, stats,
        W2s, b2s, W2a, b2a, (float*)d_out);
}